// Round 1
// baseline (66.476 us; speedup 1.0000x reference)
//
#include <hip/hip_runtime.h>
#include <hip/hip_bf16.h>

// Problem constants (fixed by the reference)
constexpr int B = 1024, S = 128, E = 256, C = 256, T = 12;

typedef short s8v __attribute__((ext_vector_type(8)));   // 8 x bf16 bits (4 VGPRs)
typedef short s4v __attribute__((ext_vector_type(4)));
typedef float f4v __attribute__((ext_vector_type(4)));

__device__ __forceinline__ short f2bf(float f) {
    unsigned u = __builtin_bit_cast(unsigned, f);
    unsigned r = (u + 0x7FFFu + ((u >> 16) & 1u)) >> 16;
    return (short)r;
}

// ---------------- Kernel 1: cast fp32 inputs to bf16 working buffers ----------------
// enc[t][b][e] = z[b][ts+1+t][e]; cl[b][c] = c[b][ts][c]; wbf = Wk_w flat
__global__ __launch_bounds__(256) void cast_kernel(
    const float* __restrict__ z, const float* __restrict__ c,
    const float* __restrict__ wk, const int* __restrict__ tsp,
    short* __restrict__ enc, short* __restrict__ cl, short* __restrict__ wbf)
{
    const int ts = tsp[0];
    const int N1 = T * B * E;        // 3145728
    const int N2 = B * C;            // 262144
    const int N3 = T * E * C;        // 786432
    int i4 = (blockIdx.x * 256 + threadIdx.x) * 4;
    if (i4 >= N1 + N2 + N3) return;

    const float4* src;
    short* dst;
    if (i4 < N1) {
        int t = i4 >> 18;            // /(B*E) = 2^18
        int rem = i4 & (B * E - 1);
        int b = rem >> 8;            // /E
        int e = rem & (E - 1);
        src = reinterpret_cast<const float4*>(z + (size_t)b * S * E + (size_t)(ts + 1 + t) * E + e);
        dst = enc + i4;
    } else if (i4 < N1 + N2) {
        int i2 = i4 - N1;
        int b = i2 >> 8;
        int cc = i2 & (C - 1);
        src = reinterpret_cast<const float4*>(c + (size_t)b * S * C + (size_t)ts * C + cc);
        dst = cl + i2;
    } else {
        int i3 = i4 - N1 - N2;
        src = reinterpret_cast<const float4*>(wk + i3);
        dst = wbf + i3;
    }
    float4 v = *src;
    s4v o;
    o[0] = f2bf(v.x); o[1] = f2bf(v.y); o[2] = f2bf(v.z); o[3] = f2bf(v.w);
    *reinterpret_cast<s4v*>(dst) = o;
}

// ---------------- Kernel 2: pred[t] = c_last @ Wk_w[t]^T + Wk_b[t] (bf16 out) ----------------
// M=B (b), N=E (e), K=C. Tiles 64x64, full K in LDS, XOR-swizzled.
__global__ __launch_bounds__(256) void pred_kernel(
    const short* __restrict__ cl, const short* __restrict__ wbf,
    const float* __restrict__ wkb, short* __restrict__ pred)
{
    const int bb = blockIdx.x, eb = blockIdx.y, t = blockIdx.z;
    __shared__ __align__(16) short AS[64 * 256];
    __shared__ __align__(16) short BS[64 * 256];
    const int tid = threadIdx.x;

    // stage: 64 rows x 32 slots (16B each) per matrix
    for (int it = 0; it < 8; ++it) {
        int idx = it * 256 + tid;
        int r = idx >> 5, s = idx & 31;
        s8v va = *reinterpret_cast<const s8v*>(cl + (size_t)(bb * 64 + r) * 256 + s * 8);
        *reinterpret_cast<s8v*>(AS + r * 256 + ((s ^ (r & 7)) * 8)) = va;
        s8v vb = *reinterpret_cast<const s8v*>(wbf + (size_t)t * E * C + (size_t)(eb * 64 + r) * 256 + s * 8);
        *reinterpret_cast<s8v*>(BS + r * 256 + ((s ^ (r & 7)) * 8)) = vb;
    }
    __syncthreads();

    const int wv = tid >> 6, ln = tid & 63;
    const int wr = (wv >> 1) * 32, wc = (wv & 1) * 32;
    const int lr = ln & 15, lg = ln >> 4;
    f4v acc[2][2] = {};

    for (int kk = 0; kk < 8; ++kk) {
        int r0 = wr + lr, r1 = wr + 16 + lr;
        int c0 = wc + lr, c1 = wc + 16 + lr;
        int slot = kk * 4 + lg;
        s8v a0 = *reinterpret_cast<const s8v*>(AS + r0 * 256 + ((slot ^ (r0 & 7)) * 8));
        s8v a1 = *reinterpret_cast<const s8v*>(AS + r1 * 256 + ((slot ^ (r1 & 7)) * 8));
        s8v b0 = *reinterpret_cast<const s8v*>(BS + c0 * 256 + ((slot ^ (c0 & 7)) * 8));
        s8v b1 = *reinterpret_cast<const s8v*>(BS + c1 * 256 + ((slot ^ (c1 & 7)) * 8));
        acc[0][0] = __builtin_amdgcn_mfma_f32_16x16x32_bf16(a0, b0, acc[0][0], 0, 0, 0);
        acc[0][1] = __builtin_amdgcn_mfma_f32_16x16x32_bf16(a0, b1, acc[0][1], 0, 0, 0);
        acc[1][0] = __builtin_amdgcn_mfma_f32_16x16x32_bf16(a1, b0, acc[1][0], 0, 0, 0);
        acc[1][1] = __builtin_amdgcn_mfma_f32_16x16x32_bf16(a1, b1, acc[1][1], 0, 0, 0);
    }

    // epilogue: C layout col=lane&15, row=(lane>>4)*4+reg
    for (int m = 0; m < 2; ++m)
        for (int n = 0; n < 2; ++n)
            for (int i = 0; i < 4; ++i) {
                int bg = bb * 64 + wr + m * 16 + lg * 4 + i;
                int eg = eb * 64 + wc + n * 16 + lr;
                float v = acc[m][n][i] + wkb[t * E + eg];
                pred[(size_t)t * B * E + (size_t)bg * E + eg] = f2bf(v);
            }
}

// ---------------- Kernel 3: scores GEMM + fused online logsumexp + diag ----------------
// block = (row-block rb of 32 rows, t). Loops 8 chunks of 128 cols; K staged in 2 halves.
__global__ __launch_bounds__(256) void score_kernel(
    const short* __restrict__ enc, const short* __restrict__ pred,
    float* __restrict__ row_vals)
{
    const int rb = blockIdx.x, t = blockIdx.y;
    __shared__ __align__(16) short encS[32 * 256];     // 16 KB, full K
    __shared__ __align__(16) short predS[128 * 128];   // 32 KB, one K-half of 128 cols
    __shared__ float msd[96];                          // mrun[32], srun[32], diag[32]
    float* mrun = msd;
    float* srun = msd + 32;
    float* diag = msd + 64;
    float* scoreS = reinterpret_cast<float*>(predS);   // aliased: 32x132 floats <= 32 KB

    const int tid = threadIdx.x;
    const short* enc_t = enc + (size_t)t * B * E;
    const short* pred_t = pred + (size_t)t * B * E;

    // stage enc rows (32 x 32 slots), init running stats
    for (int it = 0; it < 4; ++it) {
        int idx = it * 256 + tid;
        int r = idx >> 5, s = idx & 31;
        s8v v = *reinterpret_cast<const s8v*>(enc_t + (size_t)(rb * 32 + r) * 256 + s * 8);
        *reinterpret_cast<s8v*>(encS + r * 256 + ((s ^ (r & 7)) * 8)) = v;
    }
    if (tid < 32) { mrun[tid] = -1e30f; srun[tid] = 0.0f; }
    __syncthreads();

    const int wv = tid >> 6, ln = tid & 63;
    const int lr = ln & 15, lg = ln >> 4;
    const int cb = wv * 32;   // wave's column base within the 128-chunk

    for (int ci = 0; ci < 8; ++ci) {
        f4v acc[2][2] = {};
        for (int kh = 0; kh < 2; ++kh) {
            // stage pred: 128 cols x 16 slots for this K-half
            for (int it = 0; it < 8; ++it) {
                int idx = it * 256 + tid;
                int r = idx >> 4, s = idx & 15;
                s8v v = *reinterpret_cast<const s8v*>(
                    pred_t + (size_t)(ci * 128 + r) * 256 + kh * 128 + s * 8);
                *reinterpret_cast<s8v*>(predS + r * 128 + ((s ^ (r & 7)) * 8)) = v;
            }
            __syncthreads();
            for (int kk = 0; kk < 4; ++kk) {
                int kk2 = kh * 4 + kk;
                int r0 = lr, r1 = 16 + lr;
                int c0 = cb + lr, c1 = cb + 16 + lr;
                int eslot = kk2 * 4 + lg;
                int pslot = kk * 4 + lg;
                s8v a0 = *reinterpret_cast<const s8v*>(encS + r0 * 256 + ((eslot ^ (r0 & 7)) * 8));
                s8v a1 = *reinterpret_cast<const s8v*>(encS + r1 * 256 + ((eslot ^ (r1 & 7)) * 8));
                s8v b0 = *reinterpret_cast<const s8v*>(predS + c0 * 128 + ((pslot ^ (c0 & 7)) * 8));
                s8v b1 = *reinterpret_cast<const s8v*>(predS + c1 * 128 + ((pslot ^ (c1 & 7)) * 8));
                acc[0][0] = __builtin_amdgcn_mfma_f32_16x16x32_bf16(a0, b0, acc[0][0], 0, 0, 0);
                acc[0][1] = __builtin_amdgcn_mfma_f32_16x16x32_bf16(a0, b1, acc[0][1], 0, 0, 0);
                acc[1][0] = __builtin_amdgcn_mfma_f32_16x16x32_bf16(a1, b0, acc[1][0], 0, 0, 0);
                acc[1][1] = __builtin_amdgcn_mfma_f32_16x16x32_bf16(a1, b1, acc[1][1], 0, 0, 0);
            }
            __syncthreads();   // all waves done reading predS before overwrite
        }
        // write chunk scores to LDS (aliased over predS)
        for (int m = 0; m < 2; ++m)
            for (int n = 0; n < 2; ++n)
                for (int i = 0; i < 4; ++i) {
                    int r_loc = m * 16 + lg * 4 + i;
                    int c_loc = cb + n * 16 + lr;
                    scoreS[r_loc * 132 + c_loc] = acc[m][n][i];
                }
        __syncthreads();
        // reduce: 8 threads per row
        {
            int r = tid >> 3, j = tid & 7;
            float mx = -1e30f;
            for (int cc = j; cc < 128; cc += 8) mx = fmaxf(mx, scoreS[r * 132 + cc]);
            mx = fmaxf(mx, __shfl_xor(mx, 1));
            mx = fmaxf(mx, __shfl_xor(mx, 2));
            mx = fmaxf(mx, __shfl_xor(mx, 4));
            float sm = 0.0f;
            for (int cc = j; cc < 128; cc += 8) sm += __expf(scoreS[r * 132 + cc] - mx);
            sm += __shfl_xor(sm, 1);
            sm += __shfl_xor(sm, 2);
            sm += __shfl_xor(sm, 4);
            if (j == 0) {
                int rg = rb * 32 + r;
                if ((rg >> 7) == ci) diag[r] = scoreS[r * 132 + (rg & 127)];
                float mo = mrun[r];
                float mn = fmaxf(mo, mx);
                srun[r] = srun[r] * __expf(mo - mn) + sm * __expf(mx - mn);
                mrun[r] = mn;
            }
        }
        __syncthreads();   // before next chunk overwrites scoreS/predS
    }

    if (tid < 32) {
        int r = tid;
        float val = diag[r] - (mrun[r] + logf(srun[r]));
        row_vals[t * B + rb * 32 + r] = val;
    }
}

// ---------------- Kernel 4: final reduction of T*B row values → scalar ----------------
__global__ __launch_bounds__(256) void reduce_kernel(const float* __restrict__ row_vals,
                                                     float* __restrict__ out)
{
    float s = 0.0f;
    for (int i = threadIdx.x; i < T * B; i += 256) s += row_vals[i];
    for (int o = 1; o < 64; o <<= 1) s += __shfl_xor(s, o);
    __shared__ float red[4];
    int wv = threadIdx.x >> 6, ln = threadIdx.x & 63;
    if (ln == 0) red[wv] = s;
    __syncthreads();
    if (threadIdx.x == 0) {
        float tot = red[0] + red[1] + red[2] + red[3];
        out[0] = -tot / (float)(B * T);
    }
}

extern "C" void kernel_launch(void* const* d_in, const int* in_sizes, int n_in,
                              void* d_out, int out_size, void* d_ws, size_t ws_size,
                              hipStream_t stream)
{
    (void)in_sizes; (void)n_in; (void)out_size; (void)ws_size;
    const float* z   = (const float*)d_in[0];
    const float* c   = (const float*)d_in[1];
    const float* wkw = (const float*)d_in[2];
    const float* wkb = (const float*)d_in[3];
    const int*   tsp = (const int*)d_in[4];

    char* w = (char*)d_ws;
    short* enc  = (short*)(w);                       // T*B*E bf16 = 6291456 B
    short* pred = (short*)(w + 6291456);             // T*B*E bf16 = 6291456 B
    short* cl   = (short*)(w + 12582912);            // B*C bf16  = 524288 B
    short* wbf  = (short*)(w + 13107200);            // T*E*C bf16 = 1572864 B
    float* rowv = (float*)(w + 14680064);            // T*B f32 = 49152 B

    cast_kernel<<<4096, 256, 0, stream>>>(z, c, wkw, tsp, enc, cl, wbf);
    pred_kernel<<<dim3(16, 4, 12), 256, 0, stream>>>(cl, wbf, wkb, pred);
    score_kernel<<<dim3(32, 12), 256, 0, stream>>>(enc, pred, rowv);
    reduce_kernel<<<1, 256, 0, stream>>>(rowv, (float*)d_out);
}

// Round 2
// 42.532 us; speedup vs baseline: 1.5630x; 1.5630x over previous
//
#include <hip/hip_runtime.h>
#include <hip/hip_bf16.h>

constexpr int B = 1024, S = 128, E = 256, C = 256, T = 12;

typedef short s8v __attribute__((ext_vector_type(8)));   // 8 x bf16 bits
typedef float f4v __attribute__((ext_vector_type(4)));

__device__ __forceinline__ short f2bf(float f) {
    unsigned u = __builtin_bit_cast(unsigned, f);
    return (short)((u + 0x7FFFu + ((u >> 16) & 1u)) >> 16);
}
__device__ __forceinline__ s8v cvt8(float4 a, float4 b) {
    s8v o;
    o[0] = f2bf(a.x); o[1] = f2bf(a.y); o[2] = f2bf(a.z); o[3] = f2bf(a.w);
    o[4] = f2bf(b.x); o[5] = f2bf(b.y); o[6] = f2bf(b.z); o[7] = f2bf(b.w);
    return o;
}

// ---------------- Kernel 1: pred[t] = c_last @ Wk_w[t]^T + Wk_b[t] (f32 in, bf16 out) ----
// M=B (b), N=E (e), K=C. 64x64 tiles, full K in LDS, XOR-swizzled. Converts f32->bf16 in staging.
__global__ __launch_bounds__(256) void pred_kernel(
    const float* __restrict__ c, const float* __restrict__ wkw,
    const float* __restrict__ wkb, const int* __restrict__ tsp,
    short* __restrict__ pred)
{
    const int bb = blockIdx.x, eb = blockIdx.y, t = blockIdx.z;
    const int ts = tsp[0];
    __shared__ __align__(16) short AS[64 * 256];
    __shared__ __align__(16) short BS[64 * 256];
    const int tid = threadIdx.x;

    for (int it = 0; it < 8; ++it) {
        int idx = it * 256 + tid;
        int r = idx >> 5, s = idx & 31;
        const float4* pa = reinterpret_cast<const float4*>(
            c + (size_t)(bb * 64 + r) * S * C + (size_t)ts * C + s * 8);
        *reinterpret_cast<s8v*>(AS + r * 256 + ((s ^ (r & 7)) * 8)) = cvt8(pa[0], pa[1]);
        const float4* pb = reinterpret_cast<const float4*>(
            wkw + ((size_t)t * E + eb * 64 + r) * C + s * 8);
        *reinterpret_cast<s8v*>(BS + r * 256 + ((s ^ (r & 7)) * 8)) = cvt8(pb[0], pb[1]);
    }
    __syncthreads();

    const int wv = tid >> 6, ln = tid & 63;
    const int wr = (wv >> 1) * 32, wc = (wv & 1) * 32;
    const int lr = ln & 15, lg = ln >> 4;
    f4v acc[2][2] = {};

    for (int kk = 0; kk < 8; ++kk) {
        int r0 = wr + lr, r1 = wr + 16 + lr;
        int c0 = wc + lr, c1 = wc + 16 + lr;
        int slot = kk * 4 + lg;
        s8v a0 = *reinterpret_cast<const s8v*>(AS + r0 * 256 + ((slot ^ (r0 & 7)) * 8));
        s8v a1 = *reinterpret_cast<const s8v*>(AS + r1 * 256 + ((slot ^ (r1 & 7)) * 8));
        s8v b0 = *reinterpret_cast<const s8v*>(BS + c0 * 256 + ((slot ^ (c0 & 7)) * 8));
        s8v b1 = *reinterpret_cast<const s8v*>(BS + c1 * 256 + ((slot ^ (c1 & 7)) * 8));
        acc[0][0] = __builtin_amdgcn_mfma_f32_16x16x32_bf16(a0, b0, acc[0][0], 0, 0, 0);
        acc[0][1] = __builtin_amdgcn_mfma_f32_16x16x32_bf16(a0, b1, acc[0][1], 0, 0, 0);
        acc[1][0] = __builtin_amdgcn_mfma_f32_16x16x32_bf16(a1, b0, acc[1][0], 0, 0, 0);
        acc[1][1] = __builtin_amdgcn_mfma_f32_16x16x32_bf16(a1, b1, acc[1][1], 0, 0, 0);
    }

    for (int m = 0; m < 2; ++m)
        for (int n = 0; n < 2; ++n)
            for (int i = 0; i < 4; ++i) {
                int bg = bb * 64 + wr + m * 16 + lg * 4 + i;
                int eg = eb * 64 + wc + n * 16 + lr;
                float v = acc[m][n][i] + wkb[t * E + eg];
                pred[(size_t)t * B * E + (size_t)bg * E + eg] = f2bf(v);
            }
}

// ---------------- Kernel 2: scores chunk GEMM + partial logsumexp + diag --------------
// block = (chunk ci of 128 cols, row-block rb of 32 rows, t). Swapped MFMA so score-row
// lands on the lane&15 axis -> in-register row reduction (no LDS score roundtrip).
__global__ __launch_bounds__(256) void score_kernel(
    const float* __restrict__ z, const short* __restrict__ pred,
    const int* __restrict__ tsp,
    float* __restrict__ part_m, float* __restrict__ part_s,
    float* __restrict__ diag_g)
{
    const int ci = blockIdx.x, rb = blockIdx.y, t = blockIdx.z;
    const int ts = tsp[0];
    __shared__ __align__(16) short encS[32 * 256];    // 16 KB
    __shared__ __align__(16) short predS[128 * 128];  // 32 KB (one K-half)
    __shared__ float pm[4][32];
    __shared__ float ps[4][32];

    const int tid = threadIdx.x;
    const short* pred_t = pred + (size_t)t * B * E;

    // stage enc rows (f32 -> bf16, swizzled)
    for (int it = 0; it < 4; ++it) {
        int idx = it * 256 + tid;
        int r = idx >> 5, s = idx & 31;
        const float4* pz = reinterpret_cast<const float4*>(
            z + (size_t)(rb * 32 + r) * S * E + (size_t)(ts + 1 + t) * E + s * 8);
        *reinterpret_cast<s8v*>(encS + r * 256 + ((s ^ (r & 7)) * 8)) = cvt8(pz[0], pz[1]);
    }

    const int wv = tid >> 6, ln = tid & 63;
    const int lr = ln & 15, lg = ln >> 4;
    const int cb = wv * 32;
    f4v acc[2][2] = {};   // [a: col-tile][b: row-tile]

    for (int kh = 0; kh < 2; ++kh) {
        // stage pred chunk for this K-half: 128 rows x 128 K (bf16 already)
        for (int it = 0; it < 8; ++it) {
            int idx = it * 256 + tid;
            int r = idx >> 4, s = idx & 15;
            s8v v = *reinterpret_cast<const s8v*>(
                pred_t + (size_t)(ci * 128 + r) * 256 + kh * 128 + s * 8);
            *reinterpret_cast<s8v*>(predS + r * 128 + ((s ^ (r & 7)) * 8)) = v;
        }
        __syncthreads();
        for (int kk = 0; kk < 4; ++kk) {
            int pslot = kk * 4 + lg;
            int eslot = kh * 16 + kk * 4 + lg;
            int pr0 = cb + lr, pr1 = cb + 16 + lr;
            int er0 = lr, er1 = 16 + lr;
            s8v p0 = *reinterpret_cast<const s8v*>(predS + pr0 * 128 + ((pslot ^ (pr0 & 7)) * 8));
            s8v p1 = *reinterpret_cast<const s8v*>(predS + pr1 * 128 + ((pslot ^ (pr1 & 7)) * 8));
            s8v e0 = *reinterpret_cast<const s8v*>(encS + er0 * 256 + ((eslot ^ (er0 & 7)) * 8));
            s8v e1 = *reinterpret_cast<const s8v*>(encS + er1 * 256 + ((eslot ^ (er1 & 7)) * 8));
            acc[0][0] = __builtin_amdgcn_mfma_f32_16x16x32_bf16(p0, e0, acc[0][0], 0, 0, 0);
            acc[0][1] = __builtin_amdgcn_mfma_f32_16x16x32_bf16(p0, e1, acc[0][1], 0, 0, 0);
            acc[1][0] = __builtin_amdgcn_mfma_f32_16x16x32_bf16(p1, e0, acc[1][0], 0, 0, 0);
            acc[1][1] = __builtin_amdgcn_mfma_f32_16x16x32_bf16(p1, e1, acc[1][1], 0, 0, 0);
        }
        if (kh == 0) __syncthreads();   // all waves done reading predS before overwrite
    }

    // acc[a][b][i] = score(row = b*16+lr, col = cb + a*16 + lg*4 + i)
    #pragma unroll
    for (int b = 0; b < 2; ++b) {
        float mx = -1e30f;
        #pragma unroll
        for (int a = 0; a < 2; ++a)
            #pragma unroll
            for (int i = 0; i < 4; ++i) mx = fmaxf(mx, acc[a][b][i]);
        mx = fmaxf(mx, __shfl_xor(mx, 16));
        mx = fmaxf(mx, __shfl_xor(mx, 32));
        float sm = 0.0f;
        #pragma unroll
        for (int a = 0; a < 2; ++a)
            #pragma unroll
            for (int i = 0; i < 4; ++i) sm += __expf(acc[a][b][i] - mx);
        sm += __shfl_xor(sm, 16);
        sm += __shfl_xor(sm, 32);
        if (lg == 0) { pm[wv][b * 16 + lr] = mx; ps[wv][b * 16 + lr] = sm; }

        // diagonal: row rg's diag col == rg; exactly one lane in one block owns it
        int rg = rb * 32 + b * 16 + lr;
        if ((rg >> 7) == ci) {
            int dl = rg & 127;
            if ((dl >> 5) == wv && ((dl >> 2) & 3) == lg) {
                float dv = 0.0f;
                #pragma unroll
                for (int a = 0; a < 2; ++a)
                    #pragma unroll
                    for (int i = 0; i < 4; ++i)
                        if (((dl >> 4) & 1) == a && (dl & 3) == i) dv = acc[a][b][i];
                diag_g[t * B + rg] = dv;
            }
        }
    }
    __syncthreads();
    if (tid < 32) {
        float M = pm[0][tid];
        for (int w = 1; w < 4; ++w) M = fmaxf(M, pm[w][tid]);
        float Ss = 0.0f;
        for (int w = 0; w < 4; ++w) Ss += ps[w][tid] * __expf(pm[w][tid] - M);
        size_t o = (size_t)ci * (T * B) + (size_t)t * B + rb * 32 + tid;
        part_m[o] = M;
        part_s[o] = Ss;
    }
}

// ---------------- Kernel 3: combine 8 chunk partials per row, block-sum ----------------
__global__ __launch_bounds__(256) void combine_kernel(
    const float* __restrict__ part_m, const float* __restrict__ part_s,
    const float* __restrict__ diag_g, float* __restrict__ bsums)
{
    int row = blockIdx.x * 256 + threadIdx.x;   // 0..12287
    float m[8], s[8];
    #pragma unroll
    for (int i = 0; i < 8; ++i) {
        m[i] = part_m[(size_t)i * (T * B) + row];
        s[i] = part_s[(size_t)i * (T * B) + row];
    }
    float M = m[0];
    #pragma unroll
    for (int i = 1; i < 8; ++i) M = fmaxf(M, m[i]);
    float Ss = 0.0f;
    #pragma unroll
    for (int i = 0; i < 8; ++i) Ss += s[i] * __expf(m[i] - M);
    float val = diag_g[row] - (M + logf(Ss));

    for (int o = 1; o < 64; o <<= 1) val += __shfl_xor(val, o);
    __shared__ float red[4];
    int wv = threadIdx.x >> 6, lnn = threadIdx.x & 63;
    if (lnn == 0) red[wv] = val;
    __syncthreads();
    if (threadIdx.x == 0) bsums[blockIdx.x] = red[0] + red[1] + red[2] + red[3];
}

// ---------------- Kernel 4: final scalar ----------------
__global__ void final_kernel(const float* __restrict__ bsums, float* __restrict__ out)
{
    float s = (threadIdx.x < 48) ? bsums[threadIdx.x] : 0.0f;
    for (int o = 1; o < 64; o <<= 1) s += __shfl_xor(s, o);
    if (threadIdx.x == 0) out[0] = -s / (float)(B * T);
}

extern "C" void kernel_launch(void* const* d_in, const int* in_sizes, int n_in,
                              void* d_out, int out_size, void* d_ws, size_t ws_size,
                              hipStream_t stream)
{
    (void)in_sizes; (void)n_in; (void)out_size; (void)ws_size;
    const float* z   = (const float*)d_in[0];
    const float* c   = (const float*)d_in[1];
    const float* wkw = (const float*)d_in[2];
    const float* wkb = (const float*)d_in[3];
    const int*   tsp = (const int*)d_in[4];

    char* w = (char*)d_ws;
    short* pred   = (short*)(w);                 // T*B*E bf16 = 6,291,456 B
    float* part_m = (float*)(w + 6291456);       // 8*T*B f32 = 393,216 B
    float* part_s = (float*)(w + 6684672);       // 8*T*B f32 = 393,216 B
    float* diag_g = (float*)(w + 7077888);       // T*B f32   =  49,152 B
    float* bsums  = (float*)(w + 7127040);       // 48 f32

    pred_kernel<<<dim3(16, 4, 12), 256, 0, stream>>>(c, wkw, wkb, tsp, pred);
    score_kernel<<<dim3(8, 32, 12), 256, 0, stream>>>(z, pred, tsp, part_m, part_s, diag_g);
    combine_kernel<<<48, 256, 0, stream>>>(part_m, part_s, diag_g, bsums);
    final_kernel<<<1, 64, 0, stream>>>(bsums, (float*)d_out);
}

// Round 3
// 38.752 us; speedup vs baseline: 1.7154x; 1.0976x over previous
//
#include <hip/hip_runtime.h>
#include <hip/hip_bf16.h>

constexpr int B = 1024, S = 128, E = 256, C = 256, T = 12;

typedef short s8v __attribute__((ext_vector_type(8)));   // 8 x bf16 bits
typedef float f4v __attribute__((ext_vector_type(4)));

__device__ __forceinline__ short f2bf(float f) {
    unsigned u = __builtin_bit_cast(unsigned, f);
    return (short)((u + 0x7FFFu + ((u >> 16) & 1u)) >> 16);
}
__device__ __forceinline__ s8v cvt8(float4 a, float4 b) {
    s8v o;
    o[0] = f2bf(a.x); o[1] = f2bf(a.y); o[2] = f2bf(a.z); o[3] = f2bf(a.w);
    o[4] = f2bf(b.x); o[5] = f2bf(b.y); o[6] = f2bf(b.z); o[7] = f2bf(b.w);
    return o;
}

// ---------------- Kernel 1: pred[t] = c_last @ Wk_w[t]^T + Wk_b[t] (f32 in, bf16 out) ----
__global__ __launch_bounds__(256) void pred_kernel(
    const float* __restrict__ c, const float* __restrict__ wkw,
    const float* __restrict__ wkb, const int* __restrict__ tsp,
    short* __restrict__ pred)
{
    const int bb = blockIdx.x, eb = blockIdx.y, t = blockIdx.z;
    const int ts = tsp[0];
    __shared__ __align__(16) short AS[64 * 256];
    __shared__ __align__(16) short BS[64 * 256];
    const int tid = threadIdx.x;

    #pragma unroll
    for (int it = 0; it < 8; ++it) {
        int idx = it * 256 + tid;
        int r = idx >> 5, s = idx & 31;
        const float4* pa = reinterpret_cast<const float4*>(
            c + (size_t)(bb * 64 + r) * S * C + (size_t)ts * C + s * 8);
        *reinterpret_cast<s8v*>(AS + r * 256 + ((s ^ (r & 7)) * 8)) = cvt8(pa[0], pa[1]);
        const float4* pb = reinterpret_cast<const float4*>(
            wkw + ((size_t)t * E + eb * 64 + r) * C + s * 8);
        *reinterpret_cast<s8v*>(BS + r * 256 + ((s ^ (r & 7)) * 8)) = cvt8(pb[0], pb[1]);
    }
    __syncthreads();

    const int wv = tid >> 6, ln = tid & 63;
    const int wr = (wv >> 1) * 32, wc = (wv & 1) * 32;
    const int lr = ln & 15, lg = ln >> 4;
    f4v acc[2][2] = {};

    #pragma unroll
    for (int kk = 0; kk < 8; ++kk) {
        int r0 = wr + lr, r1 = wr + 16 + lr;
        int c0 = wc + lr, c1 = wc + 16 + lr;
        int slot = kk * 4 + lg;
        s8v a0 = *reinterpret_cast<const s8v*>(AS + r0 * 256 + ((slot ^ (r0 & 7)) * 8));
        s8v a1 = *reinterpret_cast<const s8v*>(AS + r1 * 256 + ((slot ^ (r1 & 7)) * 8));
        s8v b0 = *reinterpret_cast<const s8v*>(BS + c0 * 256 + ((slot ^ (c0 & 7)) * 8));
        s8v b1 = *reinterpret_cast<const s8v*>(BS + c1 * 256 + ((slot ^ (c1 & 7)) * 8));
        acc[0][0] = __builtin_amdgcn_mfma_f32_16x16x32_bf16(a0, b0, acc[0][0], 0, 0, 0);
        acc[0][1] = __builtin_amdgcn_mfma_f32_16x16x32_bf16(a0, b1, acc[0][1], 0, 0, 0);
        acc[1][0] = __builtin_amdgcn_mfma_f32_16x16x32_bf16(a1, b0, acc[1][0], 0, 0, 0);
        acc[1][1] = __builtin_amdgcn_mfma_f32_16x16x32_bf16(a1, b1, acc[1][1], 0, 0, 0);
    }

    #pragma unroll
    for (int m = 0; m < 2; ++m)
        #pragma unroll
        for (int n = 0; n < 2; ++n)
            #pragma unroll
            for (int i = 0; i < 4; ++i) {
                int bg = bb * 64 + wr + m * 16 + lg * 4 + i;
                int eg = eb * 64 + wc + n * 16 + lr;
                float v = acc[m][n][i] + wkb[t * E + eg];
                pred[(size_t)t * B * E + (size_t)bg * E + eg] = f2bf(v);
            }
}

// ---------------- Kernel 2: scores tile GEMM + partial logsumexp + diag --------------
// block = (chunk ci of 256 cols, row-block rb of 64 rows, t). 512 threads, 8 waves.
// Swapped MFMA: score-row on lane&15 axis. pred staged in K-quarters; pm/ps alias predS.
__global__ __launch_bounds__(512) void score_kernel(
    const float* __restrict__ z, const short* __restrict__ pred,
    const int* __restrict__ tsp,
    float* __restrict__ part_m, float* __restrict__ part_s,
    float* __restrict__ diag_g)
{
    const int ci = blockIdx.x, rb = blockIdx.y, t = blockIdx.z;
    const int ts = tsp[0];
    __shared__ __align__(16) char SM[65536];
    short* encS  = reinterpret_cast<short*>(SM);            // 64 x 256 bf16 = 32 KB
    short* predS = reinterpret_cast<short*>(SM + 32768);    // 256 x 64 bf16 = 32 KB (K-quarter)
    float* pm = reinterpret_cast<float*>(SM + 32768);       // aliased after last MFMA
    float* ps = pm + 256;                                    // [4 col-groups][64 rows]

    const int tid = threadIdx.x;
    const short* pred_t = pred + (size_t)t * B * E;

    // stage enc rows (f32 -> bf16, swizzled): 64 rows x 32 slots
    #pragma unroll
    for (int it = 0; it < 4; ++it) {
        int idx = it * 512 + tid;
        int r = idx >> 5, s = idx & 31;
        const float4* pz = reinterpret_cast<const float4*>(
            z + (size_t)(rb * 64 + r) * S * E + (size_t)(ts + 1 + t) * E + s * 8);
        *reinterpret_cast<s8v*>(encS + r * 256 + ((s ^ (r & 7)) * 8)) = cvt8(pz[0], pz[1]);
    }

    const int wv = tid >> 6, ln = tid & 63;
    const int wc = wv & 3, wr = wv >> 2;       // 4 col-groups x 2 row-groups
    const int lr = ln & 15, lg = ln >> 4;
    f4v acc[4][2] = {};   // [a: col-tile 16][b: row-tile 16]

    for (int kq = 0; kq < 4; ++kq) {
        // stage pred K-quarter: 256 rows x 8 slots of 16B
        #pragma unroll
        for (int it = 0; it < 4; ++it) {
            int idx = it * 512 + tid;
            int r = idx >> 3, s = idx & 7;
            s8v v = *reinterpret_cast<const s8v*>(
                pred_t + (size_t)(ci * 256 + r) * 256 + kq * 64 + s * 8);
            *reinterpret_cast<s8v*>(predS + r * 64 + ((s ^ (r & 7)) * 8)) = v;
        }
        __syncthreads();
        #pragma unroll
        for (int kk = 0; kk < 2; ++kk) {
            int pslot = kk * 4 + lg;
            int eslot = kq * 8 + kk * 4 + lg;
            s8v e[2], p[4];
            #pragma unroll
            for (int b = 0; b < 2; ++b) {
                int er = wr * 32 + b * 16 + lr;
                e[b] = *reinterpret_cast<const s8v*>(encS + er * 256 + ((eslot ^ (er & 7)) * 8));
            }
            #pragma unroll
            for (int a = 0; a < 4; ++a) {
                int pr = wc * 64 + a * 16 + lr;
                p[a] = *reinterpret_cast<const s8v*>(predS + pr * 64 + ((pslot ^ (pr & 7)) * 8));
            }
            #pragma unroll
            for (int a = 0; a < 4; ++a)
                #pragma unroll
                for (int b = 0; b < 2; ++b)
                    acc[a][b] = __builtin_amdgcn_mfma_f32_16x16x32_bf16(p[a], e[b], acc[a][b], 0, 0, 0);
        }
        __syncthreads();   // waves done reading predS before next stage (and before pm alias)
    }

    // acc[a][b][i] = score(row = wr*32 + b*16 + lr, col = ci*256 + wc*64 + a*16 + lg*4 + i)
    #pragma unroll
    for (int b = 0; b < 2; ++b) {
        float mx = -1e30f;
        #pragma unroll
        for (int a = 0; a < 4; ++a)
            #pragma unroll
            for (int i = 0; i < 4; ++i) mx = fmaxf(mx, acc[a][b][i]);
        mx = fmaxf(mx, __shfl_xor(mx, 16));
        mx = fmaxf(mx, __shfl_xor(mx, 32));
        float sm = 0.0f;
        #pragma unroll
        for (int a = 0; a < 4; ++a)
            #pragma unroll
            for (int i = 0; i < 4; ++i) sm += __expf(acc[a][b][i] - mx);
        sm += __shfl_xor(sm, 16);
        sm += __shfl_xor(sm, 32);
        if (lg == 0) {
            pm[wc * 64 + wr * 32 + b * 16 + lr] = mx;
            ps[wc * 64 + wr * 32 + b * 16 + lr] = sm;
        }

        // diagonal element of this row (exactly one lane in one block owns it)
        int rg = rb * 64 + wr * 32 + b * 16 + lr;
        if ((rg >> 8) == ci) {
            int dl = rg & 255;
            if ((dl >> 6) == wc && ((dl >> 2) & 3) == lg) {
                float dv = 0.0f;
                #pragma unroll
                for (int a = 0; a < 4; ++a)
                    #pragma unroll
                    for (int i = 0; i < 4; ++i)
                        if (((dl >> 4) & 3) == a && (dl & 3) == i) dv = acc[a][b][i];
                diag_g[t * B + rg] = dv;
            }
        }
    }
    __syncthreads();
    if (tid < 64) {
        float M = pm[tid];
        #pragma unroll
        for (int w = 1; w < 4; ++w) M = fmaxf(M, pm[w * 64 + tid]);
        float Ss = 0.0f;
        #pragma unroll
        for (int w = 0; w < 4; ++w) Ss += ps[w * 64 + tid] * __expf(pm[w * 64 + tid] - M);
        size_t o = (size_t)ci * (T * B) + (size_t)t * B + rb * 64 + tid;
        part_m[o] = M;
        part_s[o] = Ss;
    }
}

// ---------------- Kernel 3: combine 4 chunk partials per row + full reduction ----------
__global__ __launch_bounds__(1024) void combine_final(
    const float* __restrict__ part_m, const float* __restrict__ part_s,
    const float* __restrict__ diag_g, float* __restrict__ out)
{
    float acc = 0.0f;
    #pragma unroll
    for (int r = 0; r < 12; ++r) {
        int row = r * 1024 + threadIdx.x;      // 0..12287
        float m0 = part_m[row], m1 = part_m[T * B + row];
        float m2 = part_m[2 * T * B + row], m3 = part_m[3 * T * B + row];
        float s0 = part_s[row], s1 = part_s[T * B + row];
        float s2 = part_s[2 * T * B + row], s3 = part_s[3 * T * B + row];
        float M = fmaxf(fmaxf(m0, m1), fmaxf(m2, m3));
        float Ss = s0 * __expf(m0 - M) + s1 * __expf(m1 - M)
                 + s2 * __expf(m2 - M) + s3 * __expf(m3 - M);
        acc += diag_g[row] - (M + logf(Ss));
    }
    for (int o = 1; o < 64; o <<= 1) acc += __shfl_xor(acc, o);
    __shared__ float red[16];
    int wv = threadIdx.x >> 6, lnn = threadIdx.x & 63;
    if (lnn == 0) red[wv] = acc;
    __syncthreads();
    if (threadIdx.x == 0) {
        float tot = 0.0f;
        #pragma unroll
        for (int w = 0; w < 16; ++w) tot += red[w];
        out[0] = -tot / (float)(B * T);
    }
}

extern "C" void kernel_launch(void* const* d_in, const int* in_sizes, int n_in,
                              void* d_out, int out_size, void* d_ws, size_t ws_size,
                              hipStream_t stream)
{
    (void)in_sizes; (void)n_in; (void)out_size; (void)ws_size;
    const float* z   = (const float*)d_in[0];
    const float* c   = (const float*)d_in[1];
    const float* wkw = (const float*)d_in[2];
    const float* wkb = (const float*)d_in[3];
    const int*   tsp = (const int*)d_in[4];

    char* w = (char*)d_ws;
    short* pred   = (short*)(w);                 // T*B*E bf16 = 6,291,456 B
    float* part_m = (float*)(w + 6291456);       // 4*T*B f32 = 196,608 B
    float* part_s = (float*)(w + 6488064);       // 4*T*B f32 = 196,608 B
    float* diag_g = (float*)(w + 6684672);       // T*B f32   =  49,152 B

    pred_kernel<<<dim3(16, 4, 12), 256, 0, stream>>>(c, wkw, wkb, tsp, pred);
    score_kernel<<<dim3(4, 16, 12), 512, 0, stream>>>(z, pred, tsp, part_m, part_s, diag_g);
    combine_final<<<1, 1024, 0, stream>>>(part_m, part_s, diag_g, (float*)d_out);
}

// Round 4
// 35.133 us; speedup vs baseline: 1.8921x; 1.1030x over previous
//
#include <hip/hip_runtime.h>
#include <hip/hip_bf16.h>

constexpr int B = 1024, S = 128, E = 256, C = 256, T = 12;

typedef short s8v __attribute__((ext_vector_type(8)));   // 8 x bf16 bits
typedef float f4v __attribute__((ext_vector_type(4)));

__device__ __forceinline__ short f2bf(float f) {
    unsigned u = __builtin_bit_cast(unsigned, f);
    return (short)((u + 0x7FFFu + ((u >> 16) & 1u)) >> 16);
}
__device__ __forceinline__ s8v cvt8(float4 a, float4 b) {
    s8v o;
    o[0] = f2bf(a.x); o[1] = f2bf(a.y); o[2] = f2bf(a.z); o[3] = f2bf(a.w);
    o[4] = f2bf(b.x); o[5] = f2bf(b.y); o[6] = f2bf(b.z); o[7] = f2bf(b.w);
    return o;
}

// ---------------- Kernel 0: cast z-slices and c_last to bf16 ----------------
// enc[t][b][e] = bf16(z[b][ts+1+t][e]); cl[b][c] = bf16(c[b][ts][c])
__global__ __launch_bounds__(256) void cast_kernel(
    const float* __restrict__ z, const float* __restrict__ c,
    const int* __restrict__ tsp,
    short* __restrict__ enc, short* __restrict__ cl)
{
    const int ts = tsp[0];
    const int N1 = T * B * E;        // 3145728
    int i8 = (blockIdx.x * 256 + threadIdx.x) * 8;
    const float4* src;
    short* dst;
    if (i8 < N1) {
        int t = i8 >> 18;
        int rem = i8 & (B * E - 1);
        int b = rem >> 8, e = rem & (E - 1);
        src = reinterpret_cast<const float4*>(z + (size_t)b * S * E + (size_t)(ts + 1 + t) * E + e);
        dst = enc + i8;
    } else {
        int i2 = i8 - N1;            // < B*C
        int b = i2 >> 8, cc = i2 & (C - 1);
        src = reinterpret_cast<const float4*>(c + (size_t)b * S * C + (size_t)ts * C + cc);
        dst = cl + i2;
    }
    *reinterpret_cast<s8v*>(dst) = cvt8(src[0], src[1]);
}

// ---------------- Kernel 1: pred[t] = c_last @ Wk_w[t]^T (NO bias - cancels in logsoftmax) --
// 128x128 tiles, 512 threads. XCD-swizzled grid: wkw tile read once per XCD L2.
__global__ __launch_bounds__(512, 2) void pred_kernel(
    const short* __restrict__ cl, const float* __restrict__ wkw,
    short* __restrict__ pred)
{
    // bijective swizzle: 192 blocks = 8 xcd * 24; pair (t,eb) clustered per xcd
    int wgid = blockIdx.x;
    int xcd = wgid & 7, q = wgid >> 3;          // q in 0..23
    int pr = xcd * 3 + (q >> 3);                // 0..23 : pair id
    int bb = q & 7;                              // c'-row block (128 rows)
    int t = pr >> 1, eb = pr & 1;                // e-col block (128 cols)

    __shared__ __align__(16) short AS[128 * 256];   // cl tile, 64 KB
    __shared__ __align__(16) short BS[128 * 256];   // wkw tile (bf16), 64 KB
    const int tid = threadIdx.x;

    #pragma unroll
    for (int it = 0; it < 8; ++it) {
        int idx = it * 512 + tid;
        int r = idx >> 5, s = idx & 31;
        s8v va = *reinterpret_cast<const s8v*>(cl + (size_t)(bb * 128 + r) * 256 + s * 8);
        *reinterpret_cast<s8v*>(AS + r * 256 + ((s ^ (r & 7)) * 8)) = va;
        const float4* pb = reinterpret_cast<const float4*>(
            wkw + ((size_t)t * E + eb * 128 + r) * 256 + s * 8);
        *reinterpret_cast<s8v*>(BS + r * 256 + ((s ^ (r & 7)) * 8)) = cvt8(pb[0], pb[1]);
    }
    __syncthreads();

    const int wv = tid >> 6, ln = tid & 63;
    const int wr = wv >> 2, wc = wv & 3;        // 2 row-groups(64) x 4 col-groups(32)
    const int lr = ln & 15, lg = ln >> 4;
    f4v acc[4][2] = {};

    #pragma unroll
    for (int kk = 0; kk < 8; ++kk) {
        int slot = kk * 4 + lg;
        s8v a[4], b[2];
        #pragma unroll
        for (int m = 0; m < 4; ++m) {
            int r = wr * 64 + m * 16 + lr;
            a[m] = *reinterpret_cast<const s8v*>(AS + r * 256 + ((slot ^ (r & 7)) * 8));
        }
        #pragma unroll
        for (int n = 0; n < 2; ++n) {
            int r = wc * 32 + n * 16 + lr;
            b[n] = *reinterpret_cast<const s8v*>(BS + r * 256 + ((slot ^ (r & 7)) * 8));
        }
        #pragma unroll
        for (int m = 0; m < 4; ++m)
            #pragma unroll
            for (int n = 0; n < 2; ++n)
                acc[m][n] = __builtin_amdgcn_mfma_f32_16x16x32_bf16(a[m], b[n], acc[m][n], 0, 0, 0);
    }

    #pragma unroll
    for (int m = 0; m < 4; ++m)
        #pragma unroll
        for (int n = 0; n < 2; ++n)
            #pragma unroll
            for (int i = 0; i < 4; ++i) {
                int bg = bb * 128 + wr * 64 + m * 16 + lg * 4 + i;   // c' row
                int eg = eb * 128 + wc * 32 + n * 16 + lr;           // e col
                pred[(size_t)t * B * E + (size_t)bg * E + eg] = f2bf(acc[m][n][i]);
            }
}

// ---------------- Kernel 2: scores tile + partial logsumexp + diag ----------------
// 64 rows x 256 cols per block, 512 threads. pred staged in K-eighths (k-slot-major,
// conflict-free), double-buffered LDS + 2-deep register prefetch, ONE barrier per eighth.
__global__ __launch_bounds__(512, 4) void score_kernel(
    const short* __restrict__ enc, const short* __restrict__ pred,
    float* __restrict__ part_m, float* __restrict__ part_s,
    float* __restrict__ diag_g)
{
    // bijective swizzle: 768 = 8 xcd * 96; (ci,t) clustered per xcd (pred chunk L2-local)
    int wgid = blockIdx.x;
    int xcd = wgid & 7, q = wgid >> 3;           // q in 0..95
    int pairid = xcd * 6 + (q >> 4);             // 0..47
    int rb = q & 15;                              // enc row-block (64 rows)
    int t = pairid >> 2, ci = pairid & 3;         // col chunk (256 cols)

    __shared__ __align__(16) char SM[65536];
    short* encS = reinterpret_cast<short*>(SM);              // 64x256 bf16 = 32 KB
    short* buf0 = reinterpret_cast<short*>(SM + 32768);      // pred eighth [4][256][8] = 16 KB
    short* buf1 = reinterpret_cast<short*>(SM + 49152);      // 16 KB
    float* pm = reinterpret_cast<float*>(SM + 32768);        // aliased after last MFMA
    float* ps = pm + 256;

    const int tid = threadIdx.x;
    const short* enc_t = enc + (size_t)t * B * E;
    const short* pred_t = pred + (size_t)t * B * E;

    // per-thread pred chunk addresses: 2 chunks of 16B per eighth
    const int h0 = tid, h1 = tid + 512;
    const int col0 = h0 >> 2, sl0 = h0 & 3;
    const int col1 = h1 >> 2, sl1 = h1 & 3;
    const short* g0 = pred_t + (size_t)(ci * 256 + col0) * 256 + sl0 * 8;
    const short* g1 = pred_t + (size_t)(ci * 256 + col1) * 256 + sl1 * 8;
    const int l0 = sl0 * 2048 + col0 * 8;   // LDS element offsets
    const int l1 = sl1 * 2048 + col1 * 8;

    // prologue: issue eighth-0 loads, stage enc, write eighth-0, issue eighth-1 loads
    s8v R0 = *reinterpret_cast<const s8v*>(g0);
    s8v R1 = *reinterpret_cast<const s8v*>(g1);
    #pragma unroll
    for (int it = 0; it < 4; ++it) {
        int idx = it * 512 + tid;
        int r = idx >> 5, s = idx & 31;
        s8v v = *reinterpret_cast<const s8v*>(enc_t + (size_t)(rb * 64 + r) * 256 + s * 8);
        *reinterpret_cast<s8v*>(encS + r * 256 + ((s ^ (r & 7)) * 8)) = v;
    }
    *reinterpret_cast<s8v*>(buf0 + l0) = R0;
    *reinterpret_cast<s8v*>(buf0 + l1) = R1;
    R0 = *reinterpret_cast<const s8v*>(g0 + 32);
    R1 = *reinterpret_cast<const s8v*>(g1 + 32);
    __syncthreads();

    const int wv = tid >> 6, ln = tid & 63;
    const int wr = wv >> 2, wc = wv & 3;          // 2 row-groups(32) x 4 col-groups(64)
    const int lr = ln & 15, lg = ln >> 4;
    f4v acc[4][2] = {};   // [a: col-tile][b: row-tile]

    #pragma unroll
    for (int ke = 0; ke < 8; ++ke) {
        short* cur = (ke & 1) ? buf1 : buf0;
        short* nxt = (ke & 1) ? buf0 : buf1;
        if (ke < 7) {   // write prefetched eighth ke+1 (reads of nxt finished at sync ke-1)
            *reinterpret_cast<s8v*>(nxt + l0) = R0;
            *reinterpret_cast<s8v*>(nxt + l1) = R1;
        }
        if (ke < 6) {   // issue loads for eighth ke+2
            R0 = *reinterpret_cast<const s8v*>(g0 + (ke + 2) * 32);
            R1 = *reinterpret_cast<const s8v*>(g1 + (ke + 2) * 32);
        }
        // MFMA on eighth ke
        s8v p[4], e[2];
        #pragma unroll
        for (int a = 0; a < 4; ++a)
            p[a] = *reinterpret_cast<const s8v*>(cur + lg * 2048 + (wc * 64 + a * 16 + lr) * 8);
        #pragma unroll
        for (int b = 0; b < 2; ++b) {
            int er = wr * 32 + b * 16 + lr;
            int sf = ke * 4 + lg;
            e[b] = *reinterpret_cast<const s8v*>(encS + er * 256 + ((sf ^ (er & 7)) * 8));
        }
        #pragma unroll
        for (int a = 0; a < 4; ++a)
            #pragma unroll
            for (int b = 0; b < 2; ++b)
                acc[a][b] = __builtin_amdgcn_mfma_f32_16x16x32_bf16(p[a], e[b], acc[a][b], 0, 0, 0);
        __syncthreads();   // joint barrier: MFMA reads done + next-eighth writes visible
    }

    // acc[a][b][i] = score(row = wr*32+b*16+lr, col = ci*256 + wc*64 + a*16 + lg*4 + i)
    #pragma unroll
    for (int b = 0; b < 2; ++b) {
        float mx = -1e30f;
        #pragma unroll
        for (int a = 0; a < 4; ++a)
            #pragma unroll
            for (int i = 0; i < 4; ++i) mx = fmaxf(mx, acc[a][b][i]);
        mx = fmaxf(mx, __shfl_xor(mx, 16));
        mx = fmaxf(mx, __shfl_xor(mx, 32));
        float sm = 0.0f;
        #pragma unroll
        for (int a = 0; a < 4; ++a)
            #pragma unroll
            for (int i = 0; i < 4; ++i) sm += __expf(acc[a][b][i] - mx);
        sm += __shfl_xor(sm, 16);
        sm += __shfl_xor(sm, 32);
        if (lg == 0) {
            pm[wc * 64 + wr * 32 + b * 16 + lr] = mx;
            ps[wc * 64 + wr * 32 + b * 16 + lr] = sm;
        }
        int rg = rb * 64 + wr * 32 + b * 16 + lr;
        if ((rg >> 8) == ci) {
            int dl = rg & 255;
            if ((dl >> 6) == wc && ((dl >> 2) & 3) == lg) {
                float dv = 0.0f;
                #pragma unroll
                for (int a = 0; a < 4; ++a)
                    #pragma unroll
                    for (int i = 0; i < 4; ++i)
                        if (((dl >> 4) & 3) == a && (dl & 3) == i) dv = acc[a][b][i];
                diag_g[t * B + rg] = dv;
            }
        }
    }
    __syncthreads();
    if (tid < 64) {
        float M = pm[tid];
        #pragma unroll
        for (int w = 1; w < 4; ++w) M = fmaxf(M, pm[w * 64 + tid]);
        float Ss = 0.0f;
        #pragma unroll
        for (int w = 0; w < 4; ++w) Ss += ps[w * 64 + tid] * __expf(pm[w * 64 + tid] - M);
        size_t o = (size_t)ci * (T * B) + (size_t)t * B + rb * 64 + tid;
        part_m[o] = M;
        part_s[o] = Ss;
    }
}

// ---------------- Kernel 3: combine 4 partials/row, 12-block partial sums --------------
__global__ __launch_bounds__(1024) void combine_kernel(
    const float* __restrict__ part_m, const float* __restrict__ part_s,
    const float* __restrict__ diag_g, float* __restrict__ bs)
{
    int row = blockIdx.x * 1024 + threadIdx.x;   // 0..12287
    float m0 = part_m[row],             m1 = part_m[T * B + row];
    float m2 = part_m[2 * T * B + row], m3 = part_m[3 * T * B + row];
    float s0 = part_s[row],             s1 = part_s[T * B + row];
    float s2 = part_s[2 * T * B + row], s3 = part_s[3 * T * B + row];
    float M = fmaxf(fmaxf(m0, m1), fmaxf(m2, m3));
    float Ss = s0 * __expf(m0 - M) + s1 * __expf(m1 - M)
             + s2 * __expf(m2 - M) + s3 * __expf(m3 - M);
    float val = diag_g[row] - (M + logf(Ss));

    for (int o = 1; o < 64; o <<= 1) val += __shfl_xor(val, o);
    __shared__ float red[16];
    int wv = threadIdx.x >> 6, lnn = threadIdx.x & 63;
    if (lnn == 0) red[wv] = val;
    __syncthreads();
    if (threadIdx.x == 0) {
        float tot = 0.0f;
        #pragma unroll
        for (int w = 0; w < 16; ++w) tot += red[w];
        bs[blockIdx.x] = tot;
    }
}

__global__ void final_kernel(const float* __restrict__ bs, float* __restrict__ out)
{
    float s = (threadIdx.x < 12) ? bs[threadIdx.x] : 0.0f;
    for (int o = 1; o < 16; o <<= 1) s += __shfl_xor(s, o);
    if (threadIdx.x == 0) out[0] = -s / (float)(B * T);
}

extern "C" void kernel_launch(void* const* d_in, const int* in_sizes, int n_in,
                              void* d_out, int out_size, void* d_ws, size_t ws_size,
                              hipStream_t stream)
{
    (void)in_sizes; (void)n_in; (void)out_size; (void)ws_size;
    const float* z   = (const float*)d_in[0];
    const float* c   = (const float*)d_in[1];
    const float* wkw = (const float*)d_in[2];
    const int*   tsp = (const int*)d_in[4];

    char* w = (char*)d_ws;
    short* enc    = (short*)(w);                 // T*B*E bf16 = 6,291,456 B
    short* pred   = (short*)(w + 6291456);       // T*B*E bf16 = 6,291,456 B
    short* cl     = (short*)(w + 12582912);      // B*C bf16  =   524,288 B
    float* part_m = (float*)(w + 13107200);      // 4*T*B f32 =   196,608 B
    float* part_s = (float*)(w + 13303808);      // 4*T*B f32 =   196,608 B
    float* diag_g = (float*)(w + 13500416);      // T*B f32   =    49,152 B
    float* bs     = (float*)(w + 13549568);      // 12 f32

    cast_kernel<<<1664, 256, 0, stream>>>(z, c, tsp, enc, cl);
    pred_kernel<<<192, 512, 0, stream>>>(cl, wkw, pred);
    score_kernel<<<768, 512, 0, stream>>>(enc, pred, part_m, part_s, diag_g);
    combine_kernel<<<12, 1024, 0, stream>>>(part_m, part_s, diag_g, bs);
    final_kernel<<<1, 64, 0, stream>>>(bs, (float*)d_out);
}